// Round 2
// baseline (6769.665 us; speedup 1.0000x reference)
//
#include <hip/hip_runtime.h>
#include <cstddef>

// ---------------------------------------------------------------------------
// CapsuleNet forward, fp32 baseline.
// ws layout (floats): y[512*256*400] | p[512*256*36] | u[512*1152*8] | logits[5120]
// ---------------------------------------------------------------------------

__device__ __forceinline__ float wave_max(float v) {
#pragma unroll
  for (int m = 1; m < 64; m <<= 1) v = fmaxf(v, __shfl_xor(v, m, 64));
  return v;
}
__device__ __forceinline__ float wave_sum(float v) {
#pragma unroll
  for (int m = 1; m < 64; m <<= 1) v += __shfl_xor(v, m, 64);
  return v;
}

// ---------------- Conv1: x(512,1,28,28) * w(256,1,9,9) + b -> y(512,256,20,20)
// grid (512, 4), block 256.  tx = oc-quad (16), ty -> (oy0, ox-group)
__global__ __launch_bounds__(256) void conv1_kernel(
    const float* __restrict__ x, const float* __restrict__ w,
    const float* __restrict__ bias, float* __restrict__ y) {
  const int b   = blockIdx.x;
  const int oc0 = blockIdx.y * 64;
  const int t   = threadIdx.x;
  const int tx  = t & 15;   // oc quad: oc = oc0 + tx*4 + j
  const int ty  = t >> 4;   // 0..15
  const int oxg = ty & 3;   // ox group of 5
  const int oy0 = ty >> 2;  // 0..3 ; oy = oy0 + 4*m

  __shared__ float x_s[784];
  __shared__ float w_s[81][68];  // [k][oc_l], pad 68 (16B-aligned float4 rows)

  for (int idx = t; idx < 784; idx += 256) x_s[idx] = x[b * 784 + idx];
  for (int idx = t; idx < 64 * 81; idx += 256) {
    const int oc_l = idx / 81, k = idx % 81;
    w_s[k][oc_l] = w[(oc0 + oc_l) * 81 + k];
  }
  __syncthreads();

  float bz[4];
#pragma unroll
  for (int j = 0; j < 4; ++j) bz[j] = bias[oc0 + tx * 4 + j];

  for (int m = 0; m < 5; ++m) {
    const int oy = oy0 + m * 4;
    float acc[4][5];
#pragma unroll
    for (int j = 0; j < 4; ++j)
#pragma unroll
      for (int pp = 0; pp < 5; ++pp) acc[j][pp] = 0.f;

#pragma unroll
    for (int ky = 0; ky < 9; ++ky) {
      float xv[13];
      const int base = (oy + ky) * 28 + oxg * 5;
#pragma unroll
      for (int jj = 0; jj < 13; ++jj) xv[jj] = x_s[base + jj];
#pragma unroll
      for (int kx = 0; kx < 9; ++kx) {
        const float4 w4 = *reinterpret_cast<const float4*>(&w_s[ky * 9 + kx][tx * 4]);
#pragma unroll
        for (int pp = 0; pp < 5; ++pp) {
          const float xval = xv[kx + pp];
          acc[0][pp] += w4.x * xval;
          acc[1][pp] += w4.y * xval;
          acc[2][pp] += w4.z * xval;
          acc[3][pp] += w4.w * xval;
        }
      }
    }
#pragma unroll
    for (int j = 0; j < 4; ++j) {
      float* yp = y + ((size_t)b * 256 + oc0 + tx * 4 + j) * 400 + oy * 20 + oxg * 5;
#pragma unroll
      for (int pp = 0; pp < 5; ++pp) yp[pp] = acc[j][pp] + bz[j];
    }
  }
}

// ---------------- Conv2: y(512,256,20,20) * w(256,256,9,9) stride2 + b -> p(512,256,6,6)
// grid (256, 4), block 192. Block covers 2 b x 64 oc x 36 px; thread 2b x 4oc x 3px.
__global__ __launch_bounds__(192) void conv2_kernel(
    const float* __restrict__ y, const float* __restrict__ w,
    const float* __restrict__ bias, float* __restrict__ p) {
  const int b0  = blockIdx.x * 2;
  const int oc0 = blockIdx.y * 64;
  const int t   = threadIdx.x;
  const int tx  = t & 15;        // oc quad
  const int ty  = t >> 4;        // 0..11
  const int oy  = ty >> 1;       // 0..5
  const int ox0 = (ty & 1) * 3;  // 0 or 3

  __shared__ float y_s[2][400];
  __shared__ float w_s[81][68];  // [k][oc_l], pad 68

  float acc[2][4][3];
#pragma unroll
  for (int bb = 0; bb < 2; ++bb)
#pragma unroll
    for (int j = 0; j < 4; ++j)
#pragma unroll
      for (int pj = 0; pj < 3; ++pj) acc[bb][j][pj] = 0.f;

  for (int ic = 0; ic < 256; ++ic) {
    for (int idx = t; idx < 800; idx += 192) {
      const int bb = idx / 400, ii = idx % 400;
      y_s[bb][ii] = y[((size_t)(b0 + bb) * 256 + ic) * 400 + ii];
    }
    for (int idx = t; idx < 5184; idx += 192) {
      const int oc_l = idx / 81, k = idx % 81;
      w_s[k][oc_l] = w[((size_t)(oc0 + oc_l) * 256 + ic) * 81 + k];
    }
    __syncthreads();

#pragma unroll
    for (int ky = 0; ky < 9; ++ky) {
      float yv[2][13];
      const int base = (2 * oy + ky) * 20 + 2 * ox0;
#pragma unroll
      for (int bb = 0; bb < 2; ++bb)
#pragma unroll
        for (int jj = 0; jj < 13; ++jj) yv[bb][jj] = y_s[bb][base + jj];
#pragma unroll
      for (int kx = 0; kx < 9; ++kx) {
        const float4 w4 = *reinterpret_cast<const float4*>(&w_s[ky * 9 + kx][tx * 4]);
#pragma unroll
        for (int bb = 0; bb < 2; ++bb)
#pragma unroll
          for (int pj = 0; pj < 3; ++pj) {
            const float yval = yv[bb][kx + 2 * pj];
            acc[bb][0][pj] += w4.x * yval;
            acc[bb][1][pj] += w4.y * yval;
            acc[bb][2][pj] += w4.z * yval;
            acc[bb][3][pj] += w4.w * yval;
          }
      }
    }
    __syncthreads();
  }

#pragma unroll
  for (int bb = 0; bb < 2; ++bb)
#pragma unroll
    for (int j = 0; j < 4; ++j) {
      const float bz = bias[oc0 + tx * 4 + j];
#pragma unroll
      for (int pj = 0; pj < 3; ++pj)
        p[((size_t)(b0 + bb) * 256 + oc0 + tx * 4 + j) * 36 + oy * 6 + ox0 + pj] =
            acc[bb][j][pj] + bz;
    }
}

// ---------------- squash over capsule dim: p(512,256,36) -> u(512,1152,8)
// u[b, r=c2*36+s, g] = squash_g( p[b, g*32+c2, s] )
__global__ __launch_bounds__(256) void squash_kernel(const float* __restrict__ p,
                                                     float* __restrict__ u) {
  const int idx = blockIdx.x * 256 + threadIdx.x;
  if (idx >= 512 * 1152) return;
  const int b = idx / 1152;
  const int r = idx % 1152;
  const int c2 = r / 36;
  const int s  = r % 36;
  const float* pb = p + (size_t)b * 9216 + c2 * 36 + s;
  float tv[8];
  float sn = 0.f;
#pragma unroll
  for (int g = 0; g < 8; ++g) {
    tv[g] = pb[(size_t)g * 32 * 36];
    sn += tv[g] * tv[g];
  }
  const float scale = sn / ((1.f + sn) * sqrtf(sn));
  float* up = u + (size_t)idx * 8;
#pragma unroll
  for (int g = 0; g < 8; ++g) up[g] = tv[g] * scale;
}

// ---------------- routing: per (b,c) block. priors (1152x16) in registers.
// grid (512, 10), block 256. thread: og = t&3 (4 o's: og*4+j), rg = t>>2 (r = rg+64k)
__global__ __launch_bounds__(256) void routing_kernel(const float* __restrict__ u,
                                                      const float* __restrict__ rw,
                                                      float* __restrict__ logits) {
  const int b    = blockIdx.x;
  const int c    = blockIdx.y;
  const int t    = threadIdx.x;
  const int og   = t & 3;
  const int rg   = t >> 2;   // 0..63
  const int lane = t & 63;
  const int wid  = t >> 6;   // 0..3

  __shared__ float u_s[1152 * 9];  // rows padded to 9 (bank-conflict)
  __shared__ float blog_s[1152];
  __shared__ float red[8];
  __shared__ float sred[64];  // [wid][16]

  for (int idx = t; idx < 1152 * 8; idx += 256)
    u_s[(idx >> 3) * 9 + (idx & 7)] = u[(size_t)b * 9216 + idx];
  for (int idx = t; idx < 1152; idx += 256) blog_s[idx] = 0.f;
  __syncthreads();

  // priors[r][og*4+j] for this thread's 18 r's
  float pr[18][4];
  const float* rwc = rw + (size_t)c * 1152 * 128;
#pragma unroll
  for (int k = 0; k < 18; ++k) {
    const int r = rg + 64 * k;
    float a0 = 0.f, a1 = 0.f, a2 = 0.f, a3 = 0.f;
#pragma unroll
    for (int i = 0; i < 8; ++i) {
      const float uv = u_s[r * 9 + i];
      const float4 w4 = *reinterpret_cast<const float4*>(rwc + (size_t)r * 128 + i * 16 + og * 4);
      a0 += uv * w4.x; a1 += uv * w4.y; a2 += uv * w4.z; a3 += uv * w4.w;
    }
    pr[k][0] = a0; pr[k][1] = a1; pr[k][2] = a2; pr[k][3] = a3;
  }

  float sn = 0.f;
  float vj[4] = {0.f, 0.f, 0.f, 0.f};

  for (int it = 0; it < 3; ++it) {
    // softmax denom over blog (axis r)
    float lmax = -3.4e38f;
    for (int idx = t; idx < 1152; idx += 256) lmax = fmaxf(lmax, blog_s[idx]);
    lmax = wave_max(lmax);
    if (lane == 0) red[wid] = lmax;
    __syncthreads();
    const float gmax = fmaxf(fmaxf(red[0], red[1]), fmaxf(red[2], red[3]));
    float lsum = 0.f;
    for (int idx = t; idx < 1152; idx += 256) lsum += expf(blog_s[idx] - gmax);
    lsum = wave_sum(lsum);
    if (lane == 0) red[4 + wid] = lsum;
    __syncthreads();
    const float ginv = 1.f / (red[4] + red[5] + red[6] + red[7]);

    // s[o] = sum_r priors[r][o] * probs[r]
    float sp0 = 0.f, sp1 = 0.f, sp2 = 0.f, sp3 = 0.f;
#pragma unroll
    for (int k = 0; k < 18; ++k) {
      const int r = rg + 64 * k;
      const float pb = expf(blog_s[r] - gmax) * ginv;
      sp0 += pr[k][0] * pb; sp1 += pr[k][1] * pb;
      sp2 += pr[k][2] * pb; sp3 += pr[k][3] * pb;
    }
#pragma unroll
    for (int m = 4; m < 64; m <<= 1) {
      sp0 += __shfl_xor(sp0, m, 64);
      sp1 += __shfl_xor(sp1, m, 64);
      sp2 += __shfl_xor(sp2, m, 64);
      sp3 += __shfl_xor(sp3, m, 64);
    }
    if (lane < 4) {
      sred[wid * 16 + lane * 4 + 0] = sp0;
      sred[wid * 16 + lane * 4 + 1] = sp1;
      sred[wid * 16 + lane * 4 + 2] = sp2;
      sred[wid * 16 + lane * 4 + 3] = sp3;
    }
    __syncthreads();

    sn = 0.f;
#pragma unroll
    for (int o = 0; o < 16; ++o) {
      const float sv = sred[o] + sred[16 + o] + sred[32 + o] + sred[48 + o];
      sn += sv * sv;
    }
    const float scale = sn / ((1.f + sn) * sqrtf(sn));
#pragma unroll
    for (int j = 0; j < 4; ++j) {
      const int o = og * 4 + j;
      vj[j] = (sred[o] + sred[16 + o] + sred[32 + o] + sred[48 + o]) * scale;
    }

    if (it < 2) {
#pragma unroll
      for (int k = 0; k < 18; ++k) {
        float bp = pr[k][0] * vj[0] + pr[k][1] * vj[1] + pr[k][2] * vj[2] + pr[k][3] * vj[3];
        bp += __shfl_xor(bp, 1, 64);
        bp += __shfl_xor(bp, 2, 64);
        if (og == 0) blog_s[rg + 64 * k] += bp;
      }
      __syncthreads();
    }
  }
  // |v| = sqrt(sum v^2) = sn/(1+sn)
  if (t == 0) logits[b * 10 + c] = sn / (1.f + sn);
}

// ---------------- final softmax over 10 classes
__global__ __launch_bounds__(256) void out_softmax_kernel(const float* __restrict__ logits,
                                                          float* __restrict__ out) {
  const int b = blockIdx.x * 256 + threadIdx.x;
  if (b >= 512) return;
  float l[10];
  float mx = -3.4e38f;
#pragma unroll
  for (int cc = 0; cc < 10; ++cc) {
    l[cc] = logits[b * 10 + cc];
    mx = fmaxf(mx, l[cc]);
  }
  float s = 0.f;
#pragma unroll
  for (int cc = 0; cc < 10; ++cc) {
    l[cc] = expf(l[cc] - mx);
    s += l[cc];
  }
  const float inv = 1.f / s;
#pragma unroll
  for (int cc = 0; cc < 10; ++cc) out[b * 10 + cc] = l[cc] * inv;
}

extern "C" void kernel_launch(void* const* d_in, const int* in_sizes, int n_in,
                              void* d_out, int out_size, void* d_ws, size_t ws_size,
                              hipStream_t stream) {
  const float* x       = (const float*)d_in[0];
  const float* conv_w  = (const float*)d_in[1];
  const float* conv_b  = (const float*)d_in[2];
  const float* prim_w  = (const float*)d_in[3];
  const float* prim_b  = (const float*)d_in[4];
  const float* route_w = (const float*)d_in[5];
  float* out = (float*)d_out;

  float* ws     = (float*)d_ws;
  float* y      = ws;                  // 52,428,800 floats
  float* p      = y + 52428800;        //  4,718,592
  float* u      = p + 4718592;         //  4,718,592
  float* logits = u + 4718592;         //  5,120

  conv1_kernel<<<dim3(512, 4), 256, 0, stream>>>(x, conv_w, conv_b, y);
  conv2_kernel<<<dim3(256, 4), 192, 0, stream>>>(y, prim_w, prim_b, p);
  squash_kernel<<<(512 * 1152 + 255) / 256, 256, 0, stream>>>(p, u);
  routing_kernel<<<dim3(512, 10), 256, 0, stream>>>(u, route_w, logits);
  out_softmax_kernel<<<2, 256, 0, stream>>>(logits, out);
}

// Round 4
// 926.674 us; speedup vs baseline: 7.3053x; 7.3053x over previous
//
#include <hip/hip_runtime.h>
#include <cstddef>

typedef _Float16 f16;
typedef _Float16 f16x4 __attribute__((ext_vector_type(4)));
typedef _Float16 f16x8 __attribute__((ext_vector_type(8)));
typedef float f32x4 __attribute__((ext_vector_type(4)));

// ---------------------------------------------------------------------------
// CapsuleNet forward.  conv2 via f16 MFMA implicit GEMM.
// ws layout: y16 f16[512*400*256] | w16 f16[81*256*256] | p f32[512*256*36]
//            | u f32[512*1152*8] | logits f32[5120]
// ---------------------------------------------------------------------------

__device__ __forceinline__ float wave_max(float v) {
#pragma unroll
  for (int m = 1; m < 64; m <<= 1) v = fmaxf(v, __shfl_xor(v, m, 64));
  return v;
}
__device__ __forceinline__ float wave_sum(float v) {
#pragma unroll
  for (int m = 1; m < 64; m <<= 1) v += __shfl_xor(v, m, 64);
  return v;
}

// ---------------- Conv1: x(512,1,28,28) * w(256,1,9,9) + b -> y16[b][px][ic] f16
__global__ __launch_bounds__(256) void conv1_kernel(
    const float* __restrict__ x, const float* __restrict__ w,
    const float* __restrict__ bias, f16* __restrict__ y16) {
  const int b   = blockIdx.x;
  const int oc0 = blockIdx.y * 64;
  const int t   = threadIdx.x;
  const int tx  = t & 15;   // oc quad: oc = oc0 + tx*4 + j
  const int ty  = t >> 4;   // 0..15
  const int oxg = ty & 3;   // ox group of 5
  const int oy0 = ty >> 2;  // 0..3 ; oy = oy0 + 4*m

  __shared__ float x_s[784];
  __shared__ float w_s[81][68];

  for (int idx = t; idx < 784; idx += 256) x_s[idx] = x[b * 784 + idx];
  for (int idx = t; idx < 64 * 81; idx += 256) {
    const int oc_l = idx / 81, k = idx % 81;
    w_s[k][oc_l] = w[(oc0 + oc_l) * 81 + k];
  }
  __syncthreads();

  float bz[4];
#pragma unroll
  for (int j = 0; j < 4; ++j) bz[j] = bias[oc0 + tx * 4 + j];

  for (int m = 0; m < 5; ++m) {
    const int oy = oy0 + m * 4;
    float acc[4][5];
#pragma unroll
    for (int j = 0; j < 4; ++j)
#pragma unroll
      for (int pp = 0; pp < 5; ++pp) acc[j][pp] = 0.f;

#pragma unroll
    for (int ky = 0; ky < 9; ++ky) {
      float xv[13];
      const int base = (oy + ky) * 28 + oxg * 5;
#pragma unroll
      for (int jj = 0; jj < 13; ++jj) xv[jj] = x_s[base + jj];
#pragma unroll
      for (int kx = 0; kx < 9; ++kx) {
        const float4 w4 = *reinterpret_cast<const float4*>(&w_s[ky * 9 + kx][tx * 4]);
#pragma unroll
        for (int pp = 0; pp < 5; ++pp) {
          const float xval = xv[kx + pp];
          acc[0][pp] += w4.x * xval;
          acc[1][pp] += w4.y * xval;
          acc[2][pp] += w4.z * xval;
          acc[3][pp] += w4.w * xval;
        }
      }
    }
#pragma unroll
    for (int pp = 0; pp < 5; ++pp) {
      f16x4 st;
#pragma unroll
      for (int j = 0; j < 4; ++j) st[j] = (f16)(acc[j][pp] + bz[j]);
      const int px = oy * 20 + oxg * 5 + pp;
      *(f16x4*)&y16[((size_t)b * 400 + px) * 256 + oc0 + tx * 4] = st;
    }
  }
}

// ---------------- weight prep: prim_w[oc][ic][81] f32 -> w16[k81][oc][ic] f16
__global__ __launch_bounds__(256) void wprep_kernel(const float* __restrict__ w,
                                                    f16* __restrict__ w16) {
  const int idx = blockIdx.x * 256 + threadIdx.x;  // 81*256*32 = 663552
  const int kk  = idx >> 13;      // / 8192
  const int rem = idx & 8191;
  const int oc  = rem >> 5;
  const int icg = rem & 31;
  f16x8 v;
#pragma unroll
  for (int j = 0; j < 8; ++j)
    v[j] = (f16)w[((size_t)(oc * 256 + icg * 8 + j)) * 81 + kk];
  *(f16x8*)&w16[((size_t)kk * 256 + oc) * 256 + icg * 8] = v;
}

// ---------------- Conv2 MFMA: 64oc x 144n per block, K = 81 x (8 ic-chunks of 32)
// grid 512 x 256 thr. XCD swizzle: 4 oc-tiles of one b-tile share an XCD.
__global__ __launch_bounds__(256, 2) void conv2_mfma(
    const f16* __restrict__ y16, const f16* __restrict__ w16,
    const float* __restrict__ bias, float* __restrict__ p) {
  const int h      = blockIdx.x;
  const int octile = (h >> 3) & 3;
  const int btile  = ((h >> 5) << 3) | (h & 7);
  const int b0     = btile * 4;
  const int oc0    = octile * 64;
  const int tid  = threadIdx.x;
  const int lane = tid & 63;
  const int wave = tid >> 6;
  const int l15  = lane & 15;
  const int kg   = lane >> 4;            // k-group 0..3
  const int aoc  = oc0 + wave * 16 + l15;  // A-operand row (oc) for this lane

  __shared__ f16 Bl[2][144 * 40];  // [n][32ic + pad8]

  f32x4 acc[9];
#pragma unroll
  for (int f = 0; f < 9; ++f) acc[f] = (f32x4){0.f, 0.f, 0.f, 0.f};

  // staging assignment: 144 rows x 4 segs of 8 f16.  576 slots over 256 thr.
  int c0, c1, c2, l0, l1, l2;
  {
    const int idxs[3] = {tid, tid + 256, tid + 512};
    int* cs[3] = {&c0, &c1, &c2};
    int* ls[3] = {&l0, &l1, &l2};
#pragma unroll
    for (int q = 0; q < 3; ++q) {
      const int idx = idxs[q] < 576 ? idxs[q] : 0;
      const int row = idx >> 2, seg = idx & 3;
      const int bb = row / 36;
      const int op = row - bb * 36;
      const int oy = op / 6;
      const int ox = op - oy * 6;
      *cs[q] = (b0 + bb) * 102400 + (40 * oy + 2 * ox) * 256 + seg * 8;
      *ls[q] = row * 40 + seg * 8;
    }
  }
  const bool h2 = (tid < 64);

  // prologue: stage step 0 (kk=0 -> ky=kx=0, ic0=0 -> koff=0)
  {
    const f16x8 v0 = *(const f16x8*)(y16 + c0);
    const f16x8 v1 = *(const f16x8*)(y16 + c1);
    f16x8 v2;
    if (h2) v2 = *(const f16x8*)(y16 + c2);
    *(f16x8*)&Bl[0][l0] = v0;
    *(f16x8*)&Bl[0][l1] = v1;
    if (h2) *(f16x8*)&Bl[0][l2] = v2;
  }

  for (int step = 0; step < 648; ++step) {
    __syncthreads();
    const int cur = step & 1;
    // issue next-step stage loads (global) before compute
    f16x8 v0, v1, v2;
    const bool more = (step + 1) < 648;
    if (more) {
      const int ns  = step + 1;
      const int nkk = ns >> 3;
      const int nky = nkk / 9;
      const int nkx = nkk - nky * 9;
      const int koff = (20 * nky + nkx) * 256 + (ns & 7) * 32;
      v0 = *(const f16x8*)(y16 + c0 + koff);
      v1 = *(const f16x8*)(y16 + c1 + koff);
      if (h2) v2 = *(const f16x8*)(y16 + c2 + koff);
    }
    // A fragment for current step (global, L2-resident)
    const int ckk = step >> 3;
    const int cic = (step & 7) * 32;
    const f16x8 a =
        *(const f16x8*)(w16 + ((size_t)ckk * 256 + aoc) * 256 + cic + kg * 8);
    // 9 B-frags from LDS + 9 MFMA
    const f16* bp = &Bl[cur][l15 * 40 + kg * 8];
#pragma unroll
    for (int f = 0; f < 9; ++f) {
      const f16x8 bfrag = *(const f16x8*)(bp + f * 16 * 40);
      acc[f] = __builtin_amdgcn_mfma_f32_16x16x32_f16(a, bfrag, acc[f], 0, 0, 0);
    }
    // write staged data for next step into the other buffer
    if (more) {
      f16* dst = Bl[cur ^ 1];
      *(f16x8*)&dst[l0] = v0;
      *(f16x8*)&dst[l1] = v1;
      if (h2) *(f16x8*)&dst[l2] = v2;
    }
  }

  // epilogue: C row = kg*4 + j (oc within wave tile), col = l15 (n within frag)
  float bz[4];
#pragma unroll
  for (int j = 0; j < 4; ++j) bz[j] = bias[oc0 + wave * 16 + kg * 4 + j];
#pragma unroll
  for (int f = 0; f < 9; ++f) {
    const int n  = f * 16 + l15;
    const int bb = n / 36;
    const int op = n - bb * 36;
    float* pp =
        p + ((size_t)(b0 + bb) * 256 + oc0 + wave * 16 + kg * 4) * 36 + op;
#pragma unroll
    for (int j = 0; j < 4; ++j) pp[j * 36] = acc[f][j] + bz[j];
  }
}

// ---------------- squash over capsule dim: p(512,256,36) -> u(512,1152,8)
__global__ __launch_bounds__(256) void squash_kernel(const float* __restrict__ p,
                                                     float* __restrict__ u) {
  const int idx = blockIdx.x * 256 + threadIdx.x;
  if (idx >= 512 * 1152) return;
  const int b = idx / 1152;
  const int r = idx % 1152;
  const int c2 = r / 36;
  const int s  = r % 36;
  const float* pb = p + (size_t)b * 9216 + c2 * 36 + s;
  float tv[8];
  float sn = 0.f;
#pragma unroll
  for (int g = 0; g < 8; ++g) {
    tv[g] = pb[(size_t)g * 32 * 36];
    sn += tv[g] * tv[g];
  }
  const float scale = sn / ((1.f + sn) * sqrtf(sn));
  float* up = u + (size_t)idx * 8;
#pragma unroll
  for (int g = 0; g < 8; ++g) up[g] = tv[g] * scale;
}

// ---------------- routing: per (b,c) block. priors (1152x16) in registers.
__global__ __launch_bounds__(256) void routing_kernel(const float* __restrict__ u,
                                                      const float* __restrict__ rw,
                                                      float* __restrict__ logits) {
  const int b    = blockIdx.x;
  const int c    = blockIdx.y;
  const int t    = threadIdx.x;
  const int og   = t & 3;
  const int rg   = t >> 2;   // 0..63
  const int lane = t & 63;
  const int wid  = t >> 6;   // 0..3

  __shared__ float u_s[1152 * 9];
  __shared__ float blog_s[1152];
  __shared__ float red[8];
  __shared__ float sred[64];

  for (int idx = t; idx < 1152 * 8; idx += 256)
    u_s[(idx >> 3) * 9 + (idx & 7)] = u[(size_t)b * 9216 + idx];
  for (int idx = t; idx < 1152; idx += 256) blog_s[idx] = 0.f;
  __syncthreads();

  float pr[18][4];
  const float* rwc = rw + (size_t)c * 1152 * 128;
#pragma unroll
  for (int k = 0; k < 18; ++k) {
    const int r = rg + 64 * k;
    float a0 = 0.f, a1 = 0.f, a2 = 0.f, a3 = 0.f;
#pragma unroll
    for (int i = 0; i < 8; ++i) {
      const float uv = u_s[r * 9 + i];
      const float4 w4 = *reinterpret_cast<const float4*>(rwc + (size_t)r * 128 + i * 16 + og * 4);
      a0 += uv * w4.x; a1 += uv * w4.y; a2 += uv * w4.z; a3 += uv * w4.w;
    }
    pr[k][0] = a0; pr[k][1] = a1; pr[k][2] = a2; pr[k][3] = a3;
  }

  float sn = 0.f;
  float vj[4] = {0.f, 0.f, 0.f, 0.f};

  for (int it = 0; it < 3; ++it) {
    float lmax = -3.4e38f;
    for (int idx = t; idx < 1152; idx += 256) lmax = fmaxf(lmax, blog_s[idx]);
    lmax = wave_max(lmax);
    if (lane == 0) red[wid] = lmax;
    __syncthreads();
    const float gmax = fmaxf(fmaxf(red[0], red[1]), fmaxf(red[2], red[3]));
    float lsum = 0.f;
    for (int idx = t; idx < 1152; idx += 256) lsum += expf(blog_s[idx] - gmax);
    lsum = wave_sum(lsum);
    if (lane == 0) red[4 + wid] = lsum;
    __syncthreads();
    const float ginv = 1.f / (red[4] + red[5] + red[6] + red[7]);

    float sp0 = 0.f, sp1 = 0.f, sp2 = 0.f, sp3 = 0.f;
#pragma unroll
    for (int k = 0; k < 18; ++k) {
      const int r = rg + 64 * k;
      const float pb = expf(blog_s[r] - gmax) * ginv;
      sp0 += pr[k][0] * pb; sp1 += pr[k][1] * pb;
      sp2 += pr[k][2] * pb; sp3 += pr[k][3] * pb;
    }
#pragma unroll
    for (int m = 4; m < 64; m <<= 1) {
      sp0 += __shfl_xor(sp0, m, 64);
      sp1 += __shfl_xor(sp1, m, 64);
      sp2 += __shfl_xor(sp2, m, 64);
      sp3 += __shfl_xor(sp3, m, 64);
    }
    if (lane < 4) {
      sred[wid * 16 + lane * 4 + 0] = sp0;
      sred[wid * 16 + lane * 4 + 1] = sp1;
      sred[wid * 16 + lane * 4 + 2] = sp2;
      sred[wid * 16 + lane * 4 + 3] = sp3;
    }
    __syncthreads();

    sn = 0.f;
#pragma unroll
    for (int o = 0; o < 16; ++o) {
      const float sv = sred[o] + sred[16 + o] + sred[32 + o] + sred[48 + o];
      sn += sv * sv;
    }
    const float scale = sn / ((1.f + sn) * sqrtf(sn));
#pragma unroll
    for (int j = 0; j < 4; ++j) {
      const int o = og * 4 + j;
      vj[j] = (sred[o] + sred[16 + o] + sred[32 + o] + sred[48 + o]) * scale;
    }

    if (it < 2) {
#pragma unroll
      for (int k = 0; k < 18; ++k) {
        float bp = pr[k][0] * vj[0] + pr[k][1] * vj[1] + pr[k][2] * vj[2] + pr[k][3] * vj[3];
        bp += __shfl_xor(bp, 1, 64);
        bp += __shfl_xor(bp, 2, 64);
        if (og == 0) blog_s[rg + 64 * k] += bp;
      }
      __syncthreads();
    }
  }
  if (t == 0) logits[b * 10 + c] = sn / (1.f + sn);
}

// ---------------- final softmax over 10 classes
__global__ __launch_bounds__(256) void out_softmax_kernel(const float* __restrict__ logits,
                                                          float* __restrict__ out) {
  const int b = blockIdx.x * 256 + threadIdx.x;
  if (b >= 512) return;
  float l[10];
  float mx = -3.4e38f;
#pragma unroll
  for (int cc = 0; cc < 10; ++cc) {
    l[cc] = logits[b * 10 + cc];
    mx = fmaxf(mx, l[cc]);
  }
  float s = 0.f;
#pragma unroll
  for (int cc = 0; cc < 10; ++cc) {
    l[cc] = expf(l[cc] - mx);
    s += l[cc];
  }
  const float inv = 1.f / s;
#pragma unroll
  for (int cc = 0; cc < 10; ++cc) out[b * 10 + cc] = l[cc] * inv;
}

extern "C" void kernel_launch(void* const* d_in, const int* in_sizes, int n_in,
                              void* d_out, int out_size, void* d_ws, size_t ws_size,
                              hipStream_t stream) {
  const float* x       = (const float*)d_in[0];
  const float* conv_w  = (const float*)d_in[1];
  const float* conv_b  = (const float*)d_in[2];
  const float* prim_w  = (const float*)d_in[3];
  const float* prim_b  = (const float*)d_in[4];
  const float* route_w = (const float*)d_in[5];
  float* out = (float*)d_out;

  f16* y16      = (f16*)d_ws;            // 52,428,800 halves
  f16* w16      = y16 + 52428800;        //  5,308,416 halves
  float* p      = (float*)(w16 + 5308416);  // 4,718,592 f32
  float* u      = p + 4718592;              // 4,718,592 f32
  float* logits = u + 4718592;              // 5,120 f32

  conv1_kernel<<<dim3(512, 4), 256, 0, stream>>>(x, conv_w, conv_b, y16);
  wprep_kernel<<<2592, 256, 0, stream>>>(prim_w, w16);
  conv2_mfma<<<512, 256, 0, stream>>>(y16, w16, prim_b, p);
  squash_kernel<<<(512 * 1152 + 255) / 256, 256, 0, stream>>>(p, u);
  routing_kernel<<<dim3(512, 10), 256, 0, stream>>>(u, route_w, logits);
  out_softmax_kernel<<<2, 256, 0, stream>>>(logits, out);
}

// Round 5
// 866.963 us; speedup vs baseline: 7.8085x; 1.0689x over previous
//
#include <hip/hip_runtime.h>
#include <cstddef>

typedef _Float16 f16;
typedef _Float16 f16x4 __attribute__((ext_vector_type(4)));
typedef _Float16 f16x8 __attribute__((ext_vector_type(8)));
typedef float f32x4 __attribute__((ext_vector_type(4)));

// ---------------------------------------------------------------------------
// CapsuleNet forward.  conv2 via f16 MFMA implicit GEMM, split-K=4 over ic.
// ws layout: y16 f16[512*400*256] | w16 f16[81*256*256]
//            | p4 f32[4][512*256*36] | u f32[512*1152*8] | logits f32[5120]
// total ~210 MB (proven ws >= 247 MB by round-0 fp32 baseline)
// ---------------------------------------------------------------------------

__device__ __forceinline__ float wave_max(float v) {
#pragma unroll
  for (int m = 1; m < 64; m <<= 1) v = fmaxf(v, __shfl_xor(v, m, 64));
  return v;
}
__device__ __forceinline__ float wave_sum(float v) {
#pragma unroll
  for (int m = 1; m < 64; m <<= 1) v += __shfl_xor(v, m, 64);
  return v;
}

// ---------------- Conv1: x(512,1,28,28) * w(256,1,9,9) + b -> y16[b][px][ic] f16
__global__ __launch_bounds__(256) void conv1_kernel(
    const float* __restrict__ x, const float* __restrict__ w,
    const float* __restrict__ bias, f16* __restrict__ y16) {
  const int b   = blockIdx.x;
  const int oc0 = blockIdx.y * 64;
  const int t   = threadIdx.x;
  const int tx  = t & 15;   // oc quad: oc = oc0 + tx*4 + j
  const int ty  = t >> 4;   // 0..15
  const int oxg = ty & 3;   // ox group of 5
  const int oy0 = ty >> 2;  // 0..3 ; oy = oy0 + 4*m

  __shared__ float x_s[784];
  __shared__ float w_s[81][68];

  for (int idx = t; idx < 784; idx += 256) x_s[idx] = x[b * 784 + idx];
  for (int idx = t; idx < 64 * 81; idx += 256) {
    const int oc_l = idx / 81, k = idx % 81;
    w_s[k][oc_l] = w[(oc0 + oc_l) * 81 + k];
  }
  __syncthreads();

  float bz[4];
#pragma unroll
  for (int j = 0; j < 4; ++j) bz[j] = bias[oc0 + tx * 4 + j];

  for (int m = 0; m < 5; ++m) {
    const int oy = oy0 + m * 4;
    float acc[4][5];
#pragma unroll
    for (int j = 0; j < 4; ++j)
#pragma unroll
      for (int pp = 0; pp < 5; ++pp) acc[j][pp] = 0.f;

#pragma unroll
    for (int ky = 0; ky < 9; ++ky) {
      float xv[13];
      const int base = (oy + ky) * 28 + oxg * 5;
#pragma unroll
      for (int jj = 0; jj < 13; ++jj) xv[jj] = x_s[base + jj];
#pragma unroll
      for (int kx = 0; kx < 9; ++kx) {
        const float4 w4 = *reinterpret_cast<const float4*>(&w_s[ky * 9 + kx][tx * 4]);
#pragma unroll
        for (int pp = 0; pp < 5; ++pp) {
          const float xval = xv[kx + pp];
          acc[0][pp] += w4.x * xval;
          acc[1][pp] += w4.y * xval;
          acc[2][pp] += w4.z * xval;
          acc[3][pp] += w4.w * xval;
        }
      }
    }
#pragma unroll
    for (int pp = 0; pp < 5; ++pp) {
      f16x4 st;
#pragma unroll
      for (int j = 0; j < 4; ++j) st[j] = (f16)(acc[j][pp] + bz[j]);
      const int px = oy * 20 + oxg * 5 + pp;
      *(f16x4*)&y16[((size_t)b * 400 + px) * 256 + oc0 + tx * 4] = st;
    }
  }
}

// ---------------- weight prep: prim_w[oc][ic][81] f32 -> w16[k81][oc][ic] f16
__global__ __launch_bounds__(256) void wprep_kernel(const float* __restrict__ w,
                                                    f16* __restrict__ w16) {
  const int idx = blockIdx.x * 256 + threadIdx.x;  // 81*256*32 = 663552
  const int kk  = idx >> 13;      // / 8192
  const int rem = idx & 8191;
  const int oc  = rem >> 5;
  const int icg = rem & 31;
  f16x8 v;
#pragma unroll
  for (int j = 0; j < 8; ++j)
    v[j] = (f16)w[((size_t)(oc * 256 + icg * 8 + j)) * 81 + kk];
  *(f16x8*)&w16[((size_t)kk * 256 + oc) * 256 + icg * 8] = v;
}

// ---------------- Conv2 MFMA: 64oc x 144n per block, split-K=4 over ic.
// grid 2048 = variant(16: octile*4+ks) * 128 bt.  h%8 = bt%8 -> variants of a
// b-tile co-located per XCD.  162 steps of K=32 per block.  A reg-prefetched.
__global__ __launch_bounds__(256, 6) void conv2_mfma(
    const f16* __restrict__ y16, const f16* __restrict__ w16,
    float* __restrict__ p4) {
  const int h       = blockIdx.x;
  const int bt      = h & 127;
  const int variant = h >> 7;
  const int octile  = variant >> 2;
  const int ks      = variant & 3;
  const int b0      = bt * 4;
  const int oc0     = octile * 64;
  const int cicb    = ks * 64;   // this block's 64-ic window

  const int tid  = threadIdx.x;
  const int lane = tid & 63;
  const int wave = tid >> 6;
  const int l15  = lane & 15;
  const int kg   = lane >> 4;              // k-group 0..3
  const int aoc  = oc0 + wave * 16 + l15;  // A-operand row (oc)

  __shared__ f16 Bl[2][144 * 40];  // [n][32ic + pad8]

  f32x4 acc[9];
#pragma unroll
  for (int f = 0; f < 9; ++f) acc[f] = (f32x4){0.f, 0.f, 0.f, 0.f};

  // staging: 144 rows x 4 segs of 8 f16 = 576 slots over 256 threads
  int c0, c1, c2, l0, l1, l2;
  {
    const int idxs[3] = {tid, tid + 256, tid + 512};
    int* cs[3] = {&c0, &c1, &c2};
    int* ls[3] = {&l0, &l1, &l2};
#pragma unroll
    for (int q = 0; q < 3; ++q) {
      const int idx = idxs[q] < 576 ? idxs[q] : 0;
      const int row = idx >> 2, seg = idx & 3;
      const int bb = row / 36;
      const int op = row - bb * 36;
      const int oy = op / 6;
      const int ox = op - oy * 6;
      *cs[q] = (b0 + bb) * 102400 + (40 * oy + 2 * ox) * 256 + cicb + seg * 8;
      *ls[q] = row * 40 + seg * 8;
    }
  }
  const bool h2 = (tid < 64);

  // prologue: stage step 0 (kk=0, icc=0 -> koff=0); prefetch A for step 0
  {
    const f16x8 v0 = *(const f16x8*)(y16 + c0);
    const f16x8 v1 = *(const f16x8*)(y16 + c1);
    f16x8 v2;
    if (h2) v2 = *(const f16x8*)(y16 + c2);
    *(f16x8*)&Bl[0][l0] = v0;
    *(f16x8*)&Bl[0][l1] = v1;
    if (h2) *(f16x8*)&Bl[0][l2] = v2;
  }
  f16x8 a_next = *(const f16x8*)(w16 + ((size_t)aoc) * 256 + cicb + kg * 8);

  for (int step = 0; step < 162; ++step) {
    __syncthreads();
    const int cur = step & 1;
    const f16x8 a_cur = a_next;
    // issue next-step B-stage loads + A prefetch (global) before compute
    f16x8 v0, v1, v2;
    const bool more = (step + 1) < 162;
    if (more) {
      const int ns  = step + 1;
      const int nkk = ns >> 1;
      const int nky = nkk / 9;
      const int nkx = nkk - nky * 9;
      const int koff = (20 * nky + nkx) * 256 + (ns & 1) * 32;
      v0 = *(const f16x8*)(y16 + c0 + koff);
      v1 = *(const f16x8*)(y16 + c1 + koff);
      if (h2) v2 = *(const f16x8*)(y16 + c2 + koff);
      a_next = *(const f16x8*)(w16 + ((size_t)nkk * 256 + aoc) * 256 + cicb +
                               (ns & 1) * 32 + kg * 8);
    }
    // 9 B-frags from LDS + 9 MFMA (A was prefetched last step)
    const f16* bp = &Bl[cur][l15 * 40 + kg * 8];
#pragma unroll
    for (int f = 0; f < 9; ++f) {
      const f16x8 bfrag = *(const f16x8*)(bp + f * 16 * 40);
      acc[f] = __builtin_amdgcn_mfma_f32_16x16x32_f16(a_cur, bfrag, acc[f], 0, 0, 0);
    }
    // write staged data into the other buffer
    if (more) {
      f16* dst = Bl[cur ^ 1];
      *(f16x8*)&dst[l0] = v0;
      *(f16x8*)&dst[l1] = v1;
      if (h2) *(f16x8*)&dst[l2] = v2;
    }
  }

  // epilogue: partial sums (no bias; added in squash)
  float* pk = p4 + (size_t)ks * 4718592;
#pragma unroll
  for (int f = 0; f < 9; ++f) {
    const int n  = f * 16 + l15;
    const int bb = n / 36;
    const int op = n - bb * 36;
    float* pp =
        pk + ((size_t)(b0 + bb) * 256 + oc0 + wave * 16 + kg * 4) * 36 + op;
#pragma unroll
    for (int j = 0; j < 4; ++j) pp[j * 36] = acc[f][j];
  }
}

// ---------------- squash: sum 4 K-partials + bias, then squash -> u(512,1152,8)
__global__ __launch_bounds__(256) void squash_kernel(const float* __restrict__ p4,
                                                     const float* __restrict__ bias,
                                                     float* __restrict__ u) {
  const int idx = blockIdx.x * 256 + threadIdx.x;
  if (idx >= 512 * 1152) return;
  const int b = idx / 1152;
  const int r = idx % 1152;
  const int c2 = r / 36;
  const int s  = r % 36;
  const size_t base = (size_t)b * 9216 + c2 * 36 + s;
  float tv[8];
  float sn = 0.f;
#pragma unroll
  for (int g = 0; g < 8; ++g) {
    const size_t off = base + (size_t)g * 32 * 36;
    float t = p4[off] + p4[off + 4718592] + p4[off + 2 * 4718592] +
              p4[off + 3 * 4718592] + bias[g * 32 + c2];
    tv[g] = t;
    sn += t * t;
  }
  const float scale = sn / ((1.f + sn) * sqrtf(sn));
  float* up = u + (size_t)idx * 8;
#pragma unroll
  for (int g = 0; g < 8; ++g) up[g] = tv[g] * scale;
}

// ---------------- routing: per (b,c) block. priors (1152x16) in registers.
__global__ __launch_bounds__(256) void routing_kernel(const float* __restrict__ u,
                                                      const float* __restrict__ rw,
                                                      float* __restrict__ logits) {
  const int b    = blockIdx.x;
  const int c    = blockIdx.y;
  const int t    = threadIdx.x;
  const int og   = t & 3;
  const int rg   = t >> 2;   // 0..63
  const int lane = t & 63;
  const int wid  = t >> 6;   // 0..3

  __shared__ float u_s[1152 * 9];
  __shared__ float blog_s[1152];
  __shared__ float red[8];
  __shared__ float sred[64];

  for (int idx = t; idx < 1152 * 8; idx += 256)
    u_s[(idx >> 3) * 9 + (idx & 7)] = u[(size_t)b * 9216 + idx];
  for (int idx = t; idx < 1152; idx += 256) blog_s[idx] = 0.f;
  __syncthreads();

  float pr[18][4];
  const float* rwc = rw + (size_t)c * 1152 * 128;
#pragma unroll
  for (int k = 0; k < 18; ++k) {
    const int r = rg + 64 * k;
    float a0 = 0.f, a1 = 0.f, a2 = 0.f, a3 = 0.f;
#pragma unroll
    for (int i = 0; i < 8; ++i) {
      const float uv = u_s[r * 9 + i];
      const float4 w4 = *reinterpret_cast<const float4*>(rwc + (size_t)r * 128 + i * 16 + og * 4);
      a0 += uv * w4.x; a1 += uv * w4.y; a2 += uv * w4.z; a3 += uv * w4.w;
    }
    pr[k][0] = a0; pr[k][1] = a1; pr[k][2] = a2; pr[k][3] = a3;
  }

  float sn = 0.f;
  float vj[4] = {0.f, 0.f, 0.f, 0.f};

  for (int it = 0; it < 3; ++it) {
    float lmax = -3.4e38f;
    for (int idx = t; idx < 1152; idx += 256) lmax = fmaxf(lmax, blog_s[idx]);
    lmax = wave_max(lmax);
    if (lane == 0) red[wid] = lmax;
    __syncthreads();
    const float gmax = fmaxf(fmaxf(red[0], red[1]), fmaxf(red[2], red[3]));
    float lsum = 0.f;
    for (int idx = t; idx < 1152; idx += 256) lsum += expf(blog_s[idx] - gmax);
    lsum = wave_sum(lsum);
    if (lane == 0) red[4 + wid] = lsum;
    __syncthreads();
    const float ginv = 1.f / (red[4] + red[5] + red[6] + red[7]);

    float sp0 = 0.f, sp1 = 0.f, sp2 = 0.f, sp3 = 0.f;
#pragma unroll
    for (int k = 0; k < 18; ++k) {
      const int r = rg + 64 * k;
      const float pb = expf(blog_s[r] - gmax) * ginv;
      sp0 += pr[k][0] * pb; sp1 += pr[k][1] * pb;
      sp2 += pr[k][2] * pb; sp3 += pr[k][3] * pb;
    }
#pragma unroll
    for (int m = 4; m < 64; m <<= 1) {
      sp0 += __shfl_xor(sp0, m, 64);
      sp1 += __shfl_xor(sp1, m, 64);
      sp2 += __shfl_xor(sp2, m, 64);
      sp3 += __shfl_xor(sp3, m, 64);
    }
    if (lane < 4) {
      sred[wid * 16 + lane * 4 + 0] = sp0;
      sred[wid * 16 + lane * 4 + 1] = sp1;
      sred[wid * 16 + lane * 4 + 2] = sp2;
      sred[wid * 16 + lane * 4 + 3] = sp3;
    }
    __syncthreads();

    sn = 0.f;
#pragma unroll
    for (int o = 0; o < 16; ++o) {
      const float sv = sred[o] + sred[16 + o] + sred[32 + o] + sred[48 + o];
      sn += sv * sv;
    }
    const float scale = sn / ((1.f + sn) * sqrtf(sn));
#pragma unroll
    for (int j = 0; j < 4; ++j) {
      const int o = og * 4 + j;
      vj[j] = (sred[o] + sred[16 + o] + sred[32 + o] + sred[48 + o]) * scale;
    }

    if (it < 2) {
#pragma unroll
      for (int k = 0; k < 18; ++k) {
        float bp = pr[k][0] * vj[0] + pr[k][1] * vj[1] + pr[k][2] * vj[2] + pr[k][3] * vj[3];
        bp += __shfl_xor(bp, 1, 64);
        bp += __shfl_xor(bp, 2, 64);
        if (og == 0) blog_s[rg + 64 * k] += bp;
      }
      __syncthreads();
    }
  }
  if (t == 0) logits[b * 10 + c] = sn / (1.f + sn);
}

// ---------------- final softmax over 10 classes
__global__ __launch_bounds__(256) void out_softmax_kernel(const float* __restrict__ logits,
                                                          float* __restrict__ out) {
  const int b = blockIdx.x * 256 + threadIdx.x;
  if (b >= 512) return;
  float l[10];
  float mx = -3.4e38f;
#pragma unroll
  for (int cc = 0; cc < 10; ++cc) {
    l[cc] = logits[b * 10 + cc];
    mx = fmaxf(mx, l[cc]);
  }
  float s = 0.f;
#pragma unroll
  for (int cc = 0; cc < 10; ++cc) {
    l[cc] = expf(l[cc] - mx);
    s += l[cc];
  }
  const float inv = 1.f / s;
#pragma unroll
  for (int cc = 0; cc < 10; ++cc) out[b * 10 + cc] = l[cc] * inv;
}

extern "C" void kernel_launch(void* const* d_in, const int* in_sizes, int n_in,
                              void* d_out, int out_size, void* d_ws, size_t ws_size,
                              hipStream_t stream) {
  const float* x       = (const float*)d_in[0];
  const float* conv_w  = (const float*)d_in[1];
  const float* conv_b  = (const float*)d_in[2];
  const float* prim_w  = (const float*)d_in[3];
  const float* prim_b  = (const float*)d_in[4];
  const float* route_w = (const float*)d_in[5];
  float* out = (float*)d_out;

  f16* y16      = (f16*)d_ws;               // 52,428,800 halves (104.9 MB)
  f16* w16      = y16 + 52428800;           //  5,308,416 halves ( 10.6 MB)
  float* p4     = (float*)(w16 + 5308416);  //  4 x 4,718,592 f32 ( 75.5 MB)
  float* u      = p4 + 4 * 4718592;         //  4,718,592 f32     ( 18.9 MB)
  float* logits = u + 4718592;              //  5,120 f32

  conv1_kernel<<<dim3(512, 4), 256, 0, stream>>>(x, conv_w, conv_b, y16);
  wprep_kernel<<<2592, 256, 0, stream>>>(prim_w, w16);
  conv2_mfma<<<2048, 256, 0, stream>>>(y16, w16, p4);
  squash_kernel<<<(512 * 1152 + 255) / 256, 256, 0, stream>>>(p4, prim_b, u);
  routing_kernel<<<dim3(512, 10), 256, 0, stream>>>(u, route_w, logits);
  out_softmax_kernel<<<2, 256, 0, stream>>>(logits, out);
}

// Round 6
// 734.008 us; speedup vs baseline: 9.2229x; 1.1811x over previous
//
#include <hip/hip_runtime.h>
#include <cstddef>
#include <cstdint>

typedef _Float16 f16;
typedef _Float16 f16x4 __attribute__((ext_vector_type(4)));
typedef _Float16 f16x8 __attribute__((ext_vector_type(8)));
typedef float f32x4 __attribute__((ext_vector_type(4)));
typedef float f32x16 __attribute__((ext_vector_type(16)));

#define AS1 __attribute__((address_space(1)))
#define AS3 __attribute__((address_space(3)))

// ---------------------------------------------------------------------------
// CapsuleNet forward.  conv2 = f16 MFMA implicit GEMM, split-K=4,
// global_load_lds staging + counted vmcnt + raw s_barrier (T3/T4-lite),
// 32x32x16 MFMA, XOR-swizzled LDS (swizzle on global source + read side).
// ws: y16 f16[512*400*256] | w16 f16[81*256*256] | p4 f32[4][512*256*36]
//     | u f32[512*1152*8] | logits f32[5120]
// ---------------------------------------------------------------------------

__device__ __forceinline__ float wave_max(float v) {
#pragma unroll
  for (int m = 1; m < 64; m <<= 1) v = fmaxf(v, __shfl_xor(v, m, 64));
  return v;
}
__device__ __forceinline__ float wave_sum(float v) {
#pragma unroll
  for (int m = 1; m < 64; m <<= 1) v += __shfl_xor(v, m, 64);
  return v;
}

// ---------------- Conv1: x(512,1,28,28) * w(256,1,9,9) + b -> y16[b][px][ic] f16
__global__ __launch_bounds__(256) void conv1_kernel(
    const float* __restrict__ x, const float* __restrict__ w,
    const float* __restrict__ bias, f16* __restrict__ y16) {
  const int b   = blockIdx.x;
  const int oc0 = blockIdx.y * 64;
  const int t   = threadIdx.x;
  const int tx  = t & 15;
  const int ty  = t >> 4;
  const int oxg = ty & 3;
  const int oy0 = ty >> 2;

  __shared__ float x_s[784];
  __shared__ float w_s[81][68];

  for (int idx = t; idx < 784; idx += 256) x_s[idx] = x[b * 784 + idx];
  for (int idx = t; idx < 64 * 81; idx += 256) {
    const int oc_l = idx / 81, k = idx % 81;
    w_s[k][oc_l] = w[(oc0 + oc_l) * 81 + k];
  }
  __syncthreads();

  float bz[4];
#pragma unroll
  for (int j = 0; j < 4; ++j) bz[j] = bias[oc0 + tx * 4 + j];

  for (int m = 0; m < 5; ++m) {
    const int oy = oy0 + m * 4;
    float acc[4][5];
#pragma unroll
    for (int j = 0; j < 4; ++j)
#pragma unroll
      for (int pp = 0; pp < 5; ++pp) acc[j][pp] = 0.f;

#pragma unroll
    for (int ky = 0; ky < 9; ++ky) {
      float xv[13];
      const int base = (oy + ky) * 28 + oxg * 5;
#pragma unroll
      for (int jj = 0; jj < 13; ++jj) xv[jj] = x_s[base + jj];
#pragma unroll
      for (int kx = 0; kx < 9; ++kx) {
        const float4 w4 = *reinterpret_cast<const float4*>(&w_s[ky * 9 + kx][tx * 4]);
#pragma unroll
        for (int pp = 0; pp < 5; ++pp) {
          const float xval = xv[kx + pp];
          acc[0][pp] += w4.x * xval;
          acc[1][pp] += w4.y * xval;
          acc[2][pp] += w4.z * xval;
          acc[3][pp] += w4.w * xval;
        }
      }
    }
#pragma unroll
    for (int pp = 0; pp < 5; ++pp) {
      f16x4 st;
#pragma unroll
      for (int j = 0; j < 4; ++j) st[j] = (f16)(acc[j][pp] + bz[j]);
      const int px = oy * 20 + oxg * 5 + pp;
      *(f16x4*)&y16[((size_t)b * 400 + px) * 256 + oc0 + tx * 4] = st;
    }
  }
}

// ---------------- weight prep: prim_w[oc][ic][81] f32 -> w16[k81][oc][ic] f16
__global__ __launch_bounds__(256) void wprep_kernel(const float* __restrict__ w,
                                                    f16* __restrict__ w16) {
  const int idx = blockIdx.x * 256 + threadIdx.x;
  const int kk  = idx >> 13;
  const int rem = idx & 8191;
  const int oc  = rem >> 5;
  const int icg = rem & 31;
  f16x8 v;
#pragma unroll
  for (int j = 0; j < 8; ++j)
    v[j] = (f16)w[((size_t)(oc * 256 + icg * 8 + j)) * 81 + kk];
  *(f16x8*)&w16[((size_t)kk * 256 + oc) * 256 + icg * 8] = v;
}

// ---------------- Conv2 MFMA
// block tile: M=64 oc x N=128 n, K-step=64 (one ic-window per kernel tap),
// 81 steps.  4 waves as 2Mx2N, wave tile 32oc x 64n via mfma_f32_32x32x16_f16.
// LDS per buf: A 64x(64ic) = 8KB @0, B 128x(64ic) = 16KB @8192; 2 bufs = 48KB.
// Swizzle: 16B-seg' = seg ^ (row&7), applied on global src + ds_read side.
// grid = variant(16: octile*4+ks) * 144 ntiles; bid = variant*144 + ntile so
// all 16 variants of one n-tile share an XCD (bid%8 == ntile%8).
__global__ __launch_bounds__(256, 3) void conv2_mfma(
    const f16* __restrict__ y16, const f16* __restrict__ w16,
    float* __restrict__ p4) {
  const int h       = blockIdx.x;
  const int ntile   = h % 144;
  const int variant = h / 144;
  const int octile  = variant >> 2;
  const int ks      = variant & 3;
  const int oc0     = octile * 64;
  const int cicb    = ks * 64;

  const int tid  = threadIdx.x;
  const int lane = tid & 63;
  const int wave = tid >> 6;
  const int l31  = lane & 31;
  const int hi   = lane >> 5;      // 0/1
  const int wm   = wave >> 1;      // M half
  const int wn   = wave & 1;       // N half

  __shared__ char smem[49152];

  // ---- staging pointers (per-lane global base, per-wave uniform LDS offset)
  const int lr   = lane >> 3;                       // row-within-8 for staging
  const int swz  = ((lane & 7) ^ (lr & 7)) * 8;     // swizzled ic offset (f16)
  const f16* aPtr[2];
  uint32_t aLoff[2];
#pragma unroll
  for (int q = 0; q < 2; ++q) {
    const int g = wave * 2 + q;
    const int oc = oc0 + g * 8 + lr;
    aPtr[q]  = w16 + (size_t)oc * 256 + cicb + swz;
    aLoff[q] = (uint32_t)__builtin_amdgcn_readfirstlane(g * 1024);
  }
  const f16* bPtr[4];
  uint32_t bLoff[4];
#pragma unroll
  for (int q = 0; q < 4; ++q) {
    const int g   = wave * 4 + q;
    const int n   = ntile * 128 + g * 8 + lr;
    const int b   = n / 36;
    const int op  = n - b * 36;
    const int oy  = op / 6;
    const int ox  = op - oy * 6;
    bPtr[q]  = y16 + ((size_t)b * 400 + 40 * oy + 2 * ox) * 256 + cicb + swz;
    bLoff[q] = (uint32_t)__builtin_amdgcn_readfirstlane(8192 + g * 1024);
  }

  f32x16 acc0 = {0.f}, acc1 = {0.f};
#pragma unroll
  for (int r = 0; r < 16; ++r) { acc0[r] = 0.f; acc1[r] = 0.f; }

  // stage step kk into buffer bb (byte base)
  auto stage = [&](int bb, int kkn) {
    const int ky    = kkn / 9;
    const int kx    = kkn - ky * 9;
    const int koffB = (20 * ky + kx) * 256;
    const int koffA = kkn * 65536;
#pragma unroll
    for (int q = 0; q < 2; ++q)
      __builtin_amdgcn_global_load_lds(
          (const AS1 uint32_t*)(aPtr[q] + koffA),
          (AS3 uint32_t*)((AS3 char*)smem + bb + aLoff[q]), 16, 0, 0);
#pragma unroll
    for (int q = 0; q < 4; ++q)
      __builtin_amdgcn_global_load_lds(
          (const AS1 uint32_t*)(bPtr[q] + koffB),
          (AS3 uint32_t*)((AS3 char*)smem + bb + bLoff[q]), 16, 0, 0);
  };

  // ds_read bases (byte offsets within buffer)
  const int rowA  = (wm * 32 + l31) * 128;
  const int rowB  = 8192 + (wn * 64 + l31) * 128;
  const int sbase = l31 & 7;

  stage(0, 0);  // prologue: 6 loads in flight

  for (int kk = 0; kk < 81; ++kk) {
    const int cur = (kk & 1) * 24576;
    if (kk < 80) {
      stage(cur ^ 24576, kk + 1);                   // 6 more in flight (12)
      asm volatile("s_waitcnt vmcnt(6)" ::: "memory");  // cur's 6 landed
    } else {
      asm volatile("s_waitcnt vmcnt(0)" ::: "memory");
    }
    __builtin_amdgcn_s_barrier();                   // cur ready for all waves

    const char* bufp = smem + cur;
#pragma unroll
    for (int kc = 0; kc < 4; ++kc) {
      const int sw = (((kc * 2 + hi) ^ sbase) << 4);
      const f16x8 av = *(const f16x8*)(bufp + rowA + sw);
      const f16x8 b0 = *(const f16x8*)(bufp + rowB + sw);
      const f16x8 b1 = *(const f16x8*)(bufp + rowB + 32 * 128 + sw);
      acc0 = __builtin_amdgcn_mfma_f32_32x32x16_f16(av, b0, acc0, 0, 0, 0);
      acc1 = __builtin_amdgcn_mfma_f32_32x32x16_f16(av, b1, acc1, 0, 0, 0);
    }
    __builtin_amdgcn_s_barrier();  // all reads of cur done -> may restage it
  }

  // ---- epilogue: C[m][n]: m=(r&3)+8*(r>>2)+4*hi (oc), n=l31
  float* pk = p4 + (size_t)ks * 4718592;
#pragma unroll
  for (int nf = 0; nf < 2; ++nf) {
    const int n  = ntile * 128 + wn * 64 + nf * 32 + l31;
    const int b  = n / 36;
    const int op = n - b * 36;
    float* pb = pk + (size_t)b * 9216 + op;
    const f32x16 a = nf ? acc1 : acc0;
#pragma unroll
    for (int r = 0; r < 16; ++r) {
      const int oc = oc0 + wm * 32 + (r & 3) + 8 * (r >> 2) + 4 * hi;
      pb[oc * 36] = a[r];
    }
  }
}

// ---------------- squash: sum 4 K-partials + bias, squash -> u(512,1152,8)
__global__ __launch_bounds__(256) void squash_kernel(const float* __restrict__ p4,
                                                     const float* __restrict__ bias,
                                                     float* __restrict__ u) {
  const int idx = blockIdx.x * 256 + threadIdx.x;
  if (idx >= 512 * 1152) return;
  const int b = idx / 1152;
  const int r = idx % 1152;
  const int c2 = r / 36;
  const int s  = r % 36;
  const size_t base = (size_t)b * 9216 + c2 * 36 + s;
  float tv[8];
  float sn = 0.f;
#pragma unroll
  for (int g = 0; g < 8; ++g) {
    const size_t off = base + (size_t)g * 32 * 36;
    float t = p4[off] + p4[off + 4718592] + p4[off + 2 * 4718592] +
              p4[off + 3 * 4718592] + bias[g * 32 + c2];
    tv[g] = t;
    sn += t * t;
  }
  const float scale = sn / ((1.f + sn) * sqrtf(sn));
  float* up = u + (size_t)idx * 8;
#pragma unroll
  for (int g = 0; g < 8; ++g) up[g] = tv[g] * scale;
}

// ---------------- routing: per (b,c) block. priors (1152x16) in registers.
__global__ __launch_bounds__(256) void routing_kernel(const float* __restrict__ u,
                                                      const float* __restrict__ rw,
                                                      float* __restrict__ logits) {
  const int b    = blockIdx.x;
  const int c    = blockIdx.y;
  const int t    = threadIdx.x;
  const int og   = t & 3;
  const int rg   = t >> 2;
  const int lane = t & 63;
  const int wid  = t >> 6;

  __shared__ float u_s[1152 * 9];
  __shared__ float blog_s[1152];
  __shared__ float red[8];
  __shared__ float sred[64];

  for (int idx = t; idx < 1152 * 8; idx += 256)
    u_s[(idx >> 3) * 9 + (idx & 7)] = u[(size_t)b * 9216 + idx];
  for (int idx = t; idx < 1152; idx += 256) blog_s[idx] = 0.f;
  __syncthreads();

  float pr[18][4];
  const float* rwc = rw + (size_t)c * 1152 * 128;
#pragma unroll
  for (int k = 0; k < 18; ++k) {
    const int r = rg + 64 * k;
    float a0 = 0.f, a1 = 0.f, a2 = 0.f, a3 = 0.f;
#pragma unroll
    for (int i = 0; i < 8; ++i) {
      const float uv = u_s[r * 9 + i];
      const float4 w4 = *reinterpret_cast<const float4*>(rwc + (size_t)r * 128 + i * 16 + og * 4);
      a0 += uv * w4.x; a1 += uv * w4.y; a2 += uv * w4.z; a3 += uv * w4.w;
    }
    pr[k][0] = a0; pr[k][1] = a1; pr[k][2] = a2; pr[k][3] = a3;
  }

  float sn = 0.f;
  float vj[4] = {0.f, 0.f, 0.f, 0.f};

  for (int it = 0; it < 3; ++it) {
    float lmax = -3.4e38f;
    for (int idx = t; idx < 1152; idx += 256) lmax = fmaxf(lmax, blog_s[idx]);
    lmax = wave_max(lmax);
    if (lane == 0) red[wid] = lmax;
    __syncthreads();
    const float gmax = fmaxf(fmaxf(red[0], red[1]), fmaxf(red[2], red[3]));
    float lsum = 0.f;
    for (int idx = t; idx < 1152; idx += 256) lsum += expf(blog_s[idx] - gmax);
    lsum = wave_sum(lsum);
    if (lane == 0) red[4 + wid] = lsum;
    __syncthreads();
    const float ginv = 1.f / (red[4] + red[5] + red[6] + red[7]);

    float sp0 = 0.f, sp1 = 0.f, sp2 = 0.f, sp3 = 0.f;
#pragma unroll
    for (int k = 0; k < 18; ++k) {
      const int r = rg + 64 * k;
      const float pb = expf(blog_s[r] - gmax) * ginv;
      sp0 += pr[k][0] * pb; sp1 += pr[k][1] * pb;
      sp2 += pr[k][2] * pb; sp3 += pr[k][3] * pb;
    }
#pragma unroll
    for (int m = 4; m < 64; m <<= 1) {
      sp0 += __shfl_xor(sp0, m, 64);
      sp1 += __shfl_xor(sp1, m, 64);
      sp2 += __shfl_xor(sp2, m, 64);
      sp3 += __shfl_xor(sp3, m, 64);
    }
    if (lane < 4) {
      sred[wid * 16 + lane * 4 + 0] = sp0;
      sred[wid * 16 + lane * 4 + 1] = sp1;
      sred[wid * 16 + lane * 4 + 2] = sp2;
      sred[wid * 16 + lane * 4 + 3] = sp3;
    }
    __syncthreads();

    sn = 0.f;
#pragma unroll
    for (int o = 0; o < 16; ++o) {
      const float sv = sred[o] + sred[16 + o] + sred[32 + o] + sred[48 + o];
      sn += sv * sv;
    }
    const float scale = sn / ((1.f + sn) * sqrtf(sn));
#pragma unroll
    for (int j = 0; j < 4; ++j) {
      const int o = og * 4 + j;
      vj[j] = (sred[o] + sred[16 + o] + sred[32 + o] + sred[48 + o]) * scale;
    }

    if (it < 2) {
#pragma unroll
      for (int k = 0; k < 18; ++k) {
        float bp = pr[k][0] * vj[0] + pr[k][1] * vj[1] + pr[k][2] * vj[2] + pr[k][3] * vj[3];
        bp += __shfl_xor(bp, 1, 64);
        bp += __shfl_xor(bp, 2, 64);
        if (og == 0) blog_s[rg + 64 * k] += bp;
      }
      __syncthreads();
    }
  }
  if (t == 0) logits[b * 10 + c] = sn / (1.f + sn);
}

// ---------------- final softmax over 10 classes
__global__ __launch_bounds__(256) void out_softmax_kernel(const float* __restrict__ logits,
                                                          float* __restrict__ out) {
  const int b = blockIdx.x * 256 + threadIdx.x;
  if (b >= 512) return;
  float l[10];
  float mx = -3.4e38f;
#pragma unroll
  for (int cc = 0; cc < 10; ++cc) {
    l[cc] = logits[b * 10 + cc];
    mx = fmaxf(mx, l[cc]);
  }
  float s = 0.f;
#pragma unroll
  for (int cc = 0; cc < 10; ++cc) {
    l[cc] = expf(l[cc] - mx);
    s += l[cc];
  }
  const float inv = 1.f / s;
#pragma unroll
  for (int cc = 0; cc < 10; ++cc) out[b * 10 + cc] = l[cc] * inv;
}

extern "C" void kernel_launch(void* const* d_in, const int* in_sizes, int n_in,
                              void* d_out, int out_size, void* d_ws, size_t ws_size,
                              hipStream_t stream) {
  const float* x       = (const float*)d_in[0];
  const float* conv_w  = (const float*)d_in[1];
  const float* conv_b  = (const float*)d_in[2];
  const float* prim_w  = (const float*)d_in[3];
  const float* prim_b  = (const float*)d_in[4];
  const float* route_w = (const float*)d_in[5];
  float* out = (float*)d_out;

  f16* y16      = (f16*)d_ws;               // 52,428,800 halves (104.9 MB)
  f16* w16      = y16 + 52428800;           //  5,308,416 halves ( 10.6 MB)
  float* p4     = (float*)(w16 + 5308416);  //  4 x 4,718,592 f32 ( 75.5 MB)
  float* u      = p4 + 4 * 4718592;         //  4,718,592 f32     ( 18.9 MB)
  float* logits = u + 4718592;              //  5,120 f32

  conv1_kernel<<<dim3(512, 4), 256, 0, stream>>>(x, conv_w, conv_b, y16);
  wprep_kernel<<<2592, 256, 0, stream>>>(prim_w, w16);
  conv2_mfma<<<2304, 256, 0, stream>>>(y16, w16, p4);
  squash_kernel<<<(512 * 1152 + 255) / 256, 256, 0, stream>>>(p4, prim_b, u);
  routing_kernel<<<dim3(512, 10), 256, 0, stream>>>(u, route_w, logits);
  out_softmax_kernel<<<2, 256, 0, stream>>>(logits, out);
}

// Round 7
// 682.777 us; speedup vs baseline: 9.9149x; 1.0750x over previous
//
#include <hip/hip_runtime.h>
#include <cstddef>
#include <cstdint>

typedef _Float16 f16;
typedef _Float16 f16x4 __attribute__((ext_vector_type(4)));
typedef _Float16 f16x8 __attribute__((ext_vector_type(8)));
typedef float f32x4 __attribute__((ext_vector_type(4)));
typedef float f32x16 __attribute__((ext_vector_type(16)));

#define AS1 __attribute__((address_space(1)))
#define AS3 __attribute__((address_space(3)))

// ---------------------------------------------------------------------------
// CapsuleNet forward.  conv2 = f16 MFMA implicit GEMM, split-K=4,
// block tile 128oc x 128n, wave tile 64x64 (2x2 frags -> 32 FLOP/LDS-byte),
// global_load_lds + counted vmcnt + raw s_barrier, XOR-swizzled LDS.
// ws: y16 f16[512*400*256] | w16 f16[81*256*256] | p4 f32[4][512*256*36]
//     | u f32[512*1152*8] | logits f32[5120]
// ---------------------------------------------------------------------------

__device__ __forceinline__ float wave_max(float v) {
#pragma unroll
  for (int m = 1; m < 64; m <<= 1) v = fmaxf(v, __shfl_xor(v, m, 64));
  return v;
}
__device__ __forceinline__ float wave_sum(float v) {
#pragma unroll
  for (int m = 1; m < 64; m <<= 1) v += __shfl_xor(v, m, 64);
  return v;
}

// ---------------- Conv1: x(512,1,28,28) * w(256,1,9,9) + b -> y16[b][px][ic] f16
__global__ __launch_bounds__(256) void conv1_kernel(
    const float* __restrict__ x, const float* __restrict__ w,
    const float* __restrict__ bias, f16* __restrict__ y16) {
  const int b   = blockIdx.x;
  const int oc0 = blockIdx.y * 64;
  const int t   = threadIdx.x;
  const int tx  = t & 15;
  const int ty  = t >> 4;
  const int oxg = ty & 3;
  const int oy0 = ty >> 2;

  __shared__ float x_s[784];
  __shared__ float w_s[81][68];

  for (int idx = t; idx < 784; idx += 256) x_s[idx] = x[b * 784 + idx];
  for (int idx = t; idx < 64 * 81; idx += 256) {
    const int oc_l = idx / 81, k = idx % 81;
    w_s[k][oc_l] = w[(oc0 + oc_l) * 81 + k];
  }
  __syncthreads();

  float bz[4];
#pragma unroll
  for (int j = 0; j < 4; ++j) bz[j] = bias[oc0 + tx * 4 + j];

  for (int m = 0; m < 5; ++m) {
    const int oy = oy0 + m * 4;
    float acc[4][5];
#pragma unroll
    for (int j = 0; j < 4; ++j)
#pragma unroll
      for (int pp = 0; pp < 5; ++pp) acc[j][pp] = 0.f;

#pragma unroll
    for (int ky = 0; ky < 9; ++ky) {
      float xv[13];
      const int base = (oy + ky) * 28 + oxg * 5;
#pragma unroll
      for (int jj = 0; jj < 13; ++jj) xv[jj] = x_s[base + jj];
#pragma unroll
      for (int kx = 0; kx < 9; ++kx) {
        const float4 w4 = *reinterpret_cast<const float4*>(&w_s[ky * 9 + kx][tx * 4]);
#pragma unroll
        for (int pp = 0; pp < 5; ++pp) {
          const float xval = xv[kx + pp];
          acc[0][pp] += w4.x * xval;
          acc[1][pp] += w4.y * xval;
          acc[2][pp] += w4.z * xval;
          acc[3][pp] += w4.w * xval;
        }
      }
    }
#pragma unroll
    for (int pp = 0; pp < 5; ++pp) {
      f16x4 st;
#pragma unroll
      for (int j = 0; j < 4; ++j) st[j] = (f16)(acc[j][pp] + bz[j]);
      const int px = oy * 20 + oxg * 5 + pp;
      *(f16x4*)&y16[((size_t)b * 400 + px) * 256 + oc0 + tx * 4] = st;
    }
  }
}

// ---------------- weight prep: prim_w[oc][ic][81] f32 -> w16[k81][oc][ic] f16
__global__ __launch_bounds__(256) void wprep_kernel(const float* __restrict__ w,
                                                    f16* __restrict__ w16) {
  const int idx = blockIdx.x * 256 + threadIdx.x;
  const int kk  = idx >> 13;
  const int rem = idx & 8191;
  const int oc  = rem >> 5;
  const int icg = rem & 31;
  f16x8 v;
#pragma unroll
  for (int j = 0; j < 8; ++j)
    v[j] = (f16)w[((size_t)(oc * 256 + icg * 8 + j)) * 81 + kk];
  *(f16x8*)&w16[((size_t)kk * 256 + oc) * 256 + icg * 8] = v;
}

// ---------------- Conv2 MFMA
// block: M=128 oc x N=128 n, K-step=64 (one ic-window/tap), 81 steps.
// 4 waves 2Mx2N, wave tile 64x64: per K16 chunk {2 A, 2 B reads -> 4 MFMA}.
// LDS per buf: A 128x128B @0 (16KB), B @16384 (16KB); dbuf = 64KB.
// Swizzle: 16B-seg' = seg ^ (row&7) on global src + ds_read (R5-validated).
// grid = variant(8: mtile*4+ks) * 144 ntiles; bid%8 == ntile%8 -> all
// variants of one n-tile share an XCD.
__global__ __launch_bounds__(256, 2) void conv2_mfma(
    const f16* __restrict__ y16, const f16* __restrict__ w16,
    float* __restrict__ p4) {
  const int h       = blockIdx.x;
  const int ntile   = h % 144;
  const int variant = h / 144;
  const int mtile   = variant >> 2;
  const int ks      = variant & 3;
  const int oc0     = mtile * 128;
  const int cicb    = ks * 64;

  const int tid  = threadIdx.x;
  const int lane = tid & 63;
  const int wave = tid >> 6;
  const int l31  = lane & 31;
  const int hi   = lane >> 5;      // 0/1
  const int wm   = wave >> 1;      // M half
  const int wn   = wave & 1;       // N half

  __shared__ char smem[65536];

  // ---- staging: 16 A-loads + 16 B-loads per step (8 rows each), 8 per wave
  const int lr   = lane >> 3;                    // row within 8-row group
  const int swz  = ((lane & 7) ^ (lr & 7)) * 8;  // swizzled ic offset (f16)
  const f16* aPtr[4];
  uint32_t aLoff[4];
#pragma unroll
  for (int q = 0; q < 4; ++q) {
    const int g  = wave * 4 + q;       // 0..15
    const int oc = oc0 + g * 8 + lr;
    aPtr[q]  = w16 + (size_t)oc * 256 + cicb + swz;
    aLoff[q] = (uint32_t)__builtin_amdgcn_readfirstlane(g * 1024);
  }
  const f16* bPtr[4];
  uint32_t bLoff[4];
#pragma unroll
  for (int q = 0; q < 4; ++q) {
    const int g  = wave * 4 + q;
    const int n  = ntile * 128 + g * 8 + lr;
    const int b  = n / 36;
    const int op = n - b * 36;
    const int oy = op / 6;
    const int ox = op - oy * 6;
    bPtr[q]  = y16 + ((size_t)b * 400 + 40 * oy + 2 * ox) * 256 + cicb + swz;
    bLoff[q] = (uint32_t)__builtin_amdgcn_readfirstlane(16384 + g * 1024);
  }

  f32x16 acc00, acc01, acc10, acc11;
#pragma unroll
  for (int r = 0; r < 16; ++r) {
    acc00[r] = 0.f; acc01[r] = 0.f; acc10[r] = 0.f; acc11[r] = 0.f;
  }

  auto stage = [&](int bb, int kkn) {
    const int ky    = kkn / 9;
    const int kx    = kkn - ky * 9;
    const int koffB = (20 * ky + kx) * 256;
    const size_t koffA = (size_t)kkn * 65536;
#pragma unroll
    for (int q = 0; q < 4; ++q)
      __builtin_amdgcn_global_load_lds(
          (const AS1 uint32_t*)(aPtr[q] + koffA),
          (AS3 uint32_t*)((AS3 char*)smem + bb + aLoff[q]), 16, 0, 0);
#pragma unroll
    for (int q = 0; q < 4; ++q)
      __builtin_amdgcn_global_load_lds(
          (const AS1 uint32_t*)(bPtr[q] + koffB),
          (AS3 uint32_t*)((AS3 char*)smem + bb + bLoff[q]), 16, 0, 0);
  };

  // ds_read bases (byte offsets within buffer)
  const int rowA  = (wm * 64 + l31) * 128;          // a0 row; a1 = +32 rows
  const int rowB  = 16384 + (wn * 64 + l31) * 128;  // b0 row; b1 = +32 rows
  const int sbase = l31 & 7;

  stage(0, 0);  // prologue: 8 loads/wave in flight

  for (int kk = 0; kk < 81; ++kk) {
    const int cur = (kk & 1) * 32768;
    if (kk < 80) {
      stage(cur ^ 32768, kk + 1);                      // +8 -> 16 outstanding
      asm volatile("s_waitcnt vmcnt(8)" ::: "memory");  // cur's 8 landed
    } else {
      asm volatile("s_waitcnt vmcnt(0)" ::: "memory");
    }
    __builtin_amdgcn_s_barrier();  // cur ready for all waves

    const char* bufp = smem + cur;
    __builtin_amdgcn_s_setprio(1);
#pragma unroll
    for (int kc = 0; kc < 4; ++kc) {
      const int sw = (((kc * 2 + hi) ^ sbase) << 4);
      const f16x8 a0 = *(const f16x8*)(bufp + rowA + sw);
      const f16x8 a1 = *(const f16x8*)(bufp + rowA + 32 * 128 + sw);
      const f16x8 b0 = *(const f16x8*)(bufp + rowB + sw);
      const f16x8 b1 = *(const f16x8*)(bufp + rowB + 32 * 128 + sw);
      acc00 = __builtin_amdgcn_mfma_f32_32x32x16_f16(a0, b0, acc00, 0, 0, 0);
      acc01 = __builtin_amdgcn_mfma_f32_32x32x16_f16(a0, b1, acc01, 0, 0, 0);
      acc10 = __builtin_amdgcn_mfma_f32_32x32x16_f16(a1, b0, acc10, 0, 0, 0);
      acc11 = __builtin_amdgcn_mfma_f32_32x32x16_f16(a1, b1, acc11, 0, 0, 0);
    }
    __builtin_amdgcn_s_setprio(0);
    __builtin_amdgcn_s_barrier();  // reads of cur done -> may restage it
  }

  // ---- epilogue: C[m][n]: oc_m = (r&3)+8*(r>>2)+4*hi, n = l31
  float* pk = p4 + (size_t)ks * 4718592;
#pragma unroll
  for (int af = 0; af < 2; ++af) {
#pragma unroll
    for (int bf = 0; bf < 2; ++bf) {
      const f32x16 a = af ? (bf ? acc11 : acc10) : (bf ? acc01 : acc00);
      const int n  = ntile * 128 + wn * 64 + bf * 32 + l31;
      const int b  = n / 36;
      const int op = n - b * 36;
      float* pb = pk + (size_t)b * 9216 + op;
      const int ocb = oc0 + wm * 64 + af * 32 + 4 * hi;
#pragma unroll
      for (int r = 0; r < 16; ++r) {
        const int oc = ocb + (r & 3) + 8 * (r >> 2);
        pb[oc * 36] = a[r];
      }
    }
  }
}

// ---------------- squash: sum 4 K-partials + bias, squash -> u(512,1152,8)
__global__ __launch_bounds__(256) void squash_kernel(const float* __restrict__ p4,
                                                     const float* __restrict__ bias,
                                                     float* __restrict__ u) {
  const int idx = blockIdx.x * 256 + threadIdx.x;
  if (idx >= 512 * 1152) return;
  const int b = idx / 1152;
  const int r = idx % 1152;
  const int c2 = r / 36;
  const int s  = r % 36;
  const size_t base = (size_t)b * 9216 + c2 * 36 + s;
  float tv[8];
  float sn = 0.f;
#pragma unroll
  for (int g = 0; g < 8; ++g) {
    const size_t off = base + (size_t)g * 32 * 36;
    float t = p4[off] + p4[off + 4718592] + p4[off + 2 * 4718592] +
              p4[off + 3 * 4718592] + bias[g * 32 + c2];
    tv[g] = t;
    sn += t * t;
  }
  const float scale = sn / ((1.f + sn) * sqrtf(sn));
  float* up = u + (size_t)idx * 8;
#pragma unroll
  for (int g = 0; g < 8; ++g) up[g] = tv[g] * scale;
}

// ---------------- routing: per (b,c) block. priors (1152x16) in registers.
__global__ __launch_bounds__(256) void routing_kernel(const float* __restrict__ u,
                                                      const float* __restrict__ rw,
                                                      float* __restrict__ logits) {
  const int b    = blockIdx.x;
  const int c    = blockIdx.y;
  const int t    = threadIdx.x;
  const int og   = t & 3;
  const int rg   = t >> 2;
  const int lane = t & 63;
  const int wid  = t >> 6;

  __shared__ float u_s[1152 * 9];
  __shared__ float blog_s[1152];
  __shared__ float red[8];
  __shared__ float sred[64];

  for (int idx = t; idx < 1152 * 8; idx += 256)
    u_s[(idx >> 3) * 9 + (idx & 7)] = u[(size_t)b * 9216 + idx];
  for (int idx = t; idx < 1152; idx += 256) blog_s[idx] = 0.f;
  __syncthreads();

  float pr[18][4];
  const float* rwc = rw + (size_t)c * 1152 * 128;
#pragma unroll
  for (int k = 0; k < 18; ++k) {
    const int r = rg + 64 * k;
    float a0 = 0.f, a1 = 0.f, a2 = 0.f, a3 = 0.f;
#pragma unroll
    for (int i = 0; i < 8; ++i) {
      const float uv = u_s[r * 9 + i];
      const float4 w4 = *reinterpret_cast<const float4*>(rwc + (size_t)r * 128 + i * 16 + og * 4);
      a0 += uv * w4.x; a1 += uv * w4.y; a2 += uv * w4.z; a3 += uv * w4.w;
    }
    pr[k][0] = a0; pr[k][1] = a1; pr[k][2] = a2; pr[k][3] = a3;
  }

  float sn = 0.f;
  float vj[4] = {0.f, 0.f, 0.f, 0.f};

  for (int it = 0; it < 3; ++it) {
    float lmax = -3.4e38f;
    for (int idx = t; idx < 1152; idx += 256) lmax = fmaxf(lmax, blog_s[idx]);
    lmax = wave_max(lmax);
    if (lane == 0) red[wid] = lmax;
    __syncthreads();
    const float gmax = fmaxf(fmaxf(red[0], red[1]), fmaxf(red[2], red[3]));
    float lsum = 0.f;
    for (int idx = t; idx < 1152; idx += 256) lsum += expf(blog_s[idx] - gmax);
    lsum = wave_sum(lsum);
    if (lane == 0) red[4 + wid] = lsum;
    __syncthreads();
    const float ginv = 1.f / (red[4] + red[5] + red[6] + red[7]);

    float sp0 = 0.f, sp1 = 0.f, sp2 = 0.f, sp3 = 0.f;
#pragma unroll
    for (int k = 0; k < 18; ++k) {
      const int r = rg + 64 * k;
      const float pb = expf(blog_s[r] - gmax) * ginv;
      sp0 += pr[k][0] * pb; sp1 += pr[k][1] * pb;
      sp2 += pr[k][2] * pb; sp3 += pr[k][3] * pb;
    }
#pragma unroll
    for (int m = 4; m < 64; m <<= 1) {
      sp0 += __shfl_xor(sp0, m, 64);
      sp1 += __shfl_xor(sp1, m, 64);
      sp2 += __shfl_xor(sp2, m, 64);
      sp3 += __shfl_xor(sp3, m, 64);
    }
    if (lane < 4) {
      sred[wid * 16 + lane * 4 + 0] = sp0;
      sred[wid * 16 + lane * 4 + 1] = sp1;
      sred[wid * 16 + lane * 4 + 2] = sp2;
      sred[wid * 16 + lane * 4 + 3] = sp3;
    }
    __syncthreads();

    sn = 0.f;
#pragma unroll
    for (int o = 0; o < 16; ++o) {
      const float sv = sred[o] + sred[16 + o] + sred[32 + o] + sred[48 + o];
      sn += sv * sv;
    }
    const float scale = sn / ((1.f + sn) * sqrtf(sn));
#pragma unroll
    for (int j = 0; j < 4; ++j) {
      const int o = og * 4 + j;
      vj[j] = (sred[o] + sred[16 + o] + sred[32 + o] + sred[48 + o]) * scale;
    }

    if (it < 2) {
#pragma unroll
      for (int k = 0; k < 18; ++k) {
        float bp = pr[k][0] * vj[0] + pr[k][1] * vj[1] + pr[k][2] * vj[2] + pr[k][3] * vj[3];
        bp += __shfl_xor(bp, 1, 64);
        bp += __shfl_xor(bp, 2, 64);
        if (og == 0) blog_s[rg + 64 * k] += bp;
      }
      __syncthreads();
    }
  }
  if (t == 0) logits[b * 10 + c] = sn / (1.f + sn);
}

// ---------------- final softmax over 10 classes
__global__ __launch_bounds__(256) void out_softmax_kernel(const float* __restrict__ logits,
                                                          float* __restrict__ out) {
  const int b = blockIdx.x * 256 + threadIdx.x;
  if (b >= 512) return;
  float l[10];
  float mx = -3.4e38f;
#pragma unroll
  for (int cc = 0; cc < 10; ++cc) {
    l[cc] = logits[b * 10 + cc];
    mx = fmaxf(mx, l[cc]);
  }
  float s = 0.f;
#pragma unroll
  for (int cc = 0; cc < 10; ++cc) {
    l[cc] = expf(l[cc] - mx);
    s += l[cc];
  }
  const float inv = 1.f / s;
#pragma unroll
  for (int cc = 0; cc < 10; ++cc) out[b * 10 + cc] = l[cc] * inv;
}

extern "C" void kernel_launch(void* const* d_in, const int* in_sizes, int n_in,
                              void* d_out, int out_size, void* d_ws, size_t ws_size,
                              hipStream_t stream) {
  const float* x       = (const float*)d_in[0];
  const float* conv_w  = (const float*)d_in[1];
  const float* conv_b  = (const float*)d_in[2];
  const float* prim_w  = (const float*)d_in[3];
  const float* prim_b  = (const float*)d_in[4];
  const float* route_w = (const float*)d_in[5];
  float* out = (float*)d_out;

  f16* y16      = (f16*)d_ws;               // 52,428,800 halves (104.9 MB)
  f16* w16      = y16 + 52428800;           //  5,308,416 halves ( 10.6 MB)
  float* p4     = (float*)(w16 + 5308416);  //  4 x 4,718,592 f32 ( 75.5 MB)
  float* u      = p4 + 4 * 4718592;         //  4,718,592 f32     ( 18.9 MB)
  float* logits = u + 4718592;              //  5,120 f32

  conv1_kernel<<<dim3(512, 4), 256, 0, stream>>>(x, conv_w, conv_b, y16);
  wprep_kernel<<<2592, 256, 0, stream>>>(prim_w, w16);
  conv2_mfma<<<1152, 256, 0, stream>>>(y16, w16, p4);
  squash_kernel<<<(512 * 1152 + 255) / 256, 256, 0, stream>>>(p4, prim_b, u);
  routing_kernel<<<dim3(512, 10), 256, 0, stream>>>(u, route_w, logits);
  out_softmax_kernel<<<2, 256, 0, stream>>>(logits, out);
}